// Round 19
// baseline (153.542 us; speedup 1.0000x reference)
//
#include <hip/hip_runtime.h>
#include <math.h>

// PseudoGroupContrast — persistent 2-chunk blocks, cross-chunk overlap.
//
//   prep:   queue fp32 -> fp8 e4m3, MFMA-fragment-tiled, in d_ws (48 KB).
//   prepQ:  per-class queue sums (fp8) into pad rows 375..377 (tile 23).
//   main:   grid B/256, block 512 (8 waves), LDS 48 KB, lb(512,4).
//           Each block: stage qt->LDS ONCE, then TWO 128-row chunks:
//             issue chunk0 loads -> consume -> sync(qt) ->
//             ISSUE CHUNK1 LOADS (16 KB/wave, in flight) ->
//             chunk0 MFMA loop (~2500cy >> HBM latency) + epilogue ->
//             consume chunk1 (waitcnt lands here by program order) ->
//             chunk1 MFMA loop + epilogue.
//           Memory latency is hidden STRUCTURALLY (loads issued one full
//           MFMA loop before use), not by scheduler heuristics.
//           Inner loop = R16 form: 4 ds_read_b64 + 4 chained MFMA + 4 __expf
//           per tile (VGPR-lean, no spillable arrays; R18's bb[16] spilled
//           6 MB). exp via __expf (native v_mul+v_exp; exp2f = slow OCML).
//           Tile 23: lr<7 -> S1; lanes 7..9 carry S2 per class (proven).
//           per = log(exp(def2)+S1) - (S2+def2)/126,  def2 = 2*f_hat.ef_hat
//   finish: deterministic reduce of block partials -> out.

#define D       128
#define NQ      375
#define QS      125
#define INV126  (1.0f/126.0f)
#define QT_BYTES 49152

typedef __attribute__((ext_vector_type(4))) float f32x4;

#if defined(__has_builtin)
#if __has_builtin(__builtin_amdgcn_cvt_pk_fp8_f32)
#define HAVE_CVT_FP8 1
#endif
#endif

#ifndef HAVE_CVT_FP8
static __device__ __forceinline__ unsigned f2e4m3_sw(float x) {
    unsigned u = __float_as_uint(x);
    unsigned s = (u >> 24) & 0x80;
    int e = (int)((u >> 23) & 0xFF);
    unsigned m = u & 0x7FFFFF;
    if (e == 0) return s;
    int te = e - 120;
    unsigned val;
    if (te >= 1) {
        unsigned keep = m >> 20;
        unsigned rest = m & 0xFFFFF;
        keep += (rest > 0x80000) || (rest == 0x80000 && (keep & 1));
        if (keep == 8) { keep = 0; te += 1; }
        val = (te >= 16) ? 0x7E : ((unsigned)(te << 3) | keep);
    } else {
        unsigned full = m | 0x800000;
        int sh = 21 - te;
        if (sh > 31) val = 0;
        else {
            unsigned keep = full >> sh;
            unsigned rem = full & ((1u << sh) - 1);
            unsigned half = 1u << (sh - 1);
            keep += (rem > half) || (rem == half && (keep & 1));
            val = keep;
        }
    }
    return s | val;
}
#endif

static __device__ __forceinline__ unsigned pk4(float4 v) {
#ifdef HAVE_CVT_FP8
    int r = __builtin_amdgcn_cvt_pk_fp8_f32(v.x, v.y, 0, false);
    r = __builtin_amdgcn_cvt_pk_fp8_f32(v.z, v.w, r, true);
    return (unsigned)r;
#else
    return f2e4m3_sw(v.x) | (f2e4m3_sw(v.y) << 8)
         | (f2e4m3_sw(v.z) << 16) | (f2e4m3_sw(v.w) << 24);
#endif
}

static __device__ __forceinline__ unsigned char pk1(float x) {
#ifdef HAVE_CVT_FP8
    return (unsigned char)(__builtin_amdgcn_cvt_pk_fp8_f32(x, x, 0, false) & 0xff);
#else
    return (unsigned char)f2e4m3_sw(x);
#endif
}

static __device__ __forceinline__ long pk8(float gs, float4 a, float4 b) {
    float4 sa = make_float4(gs * a.x, gs * a.y, gs * a.z, gs * a.w);
    float4 sb = make_float4(gs * b.x, gs * b.y, gs * b.z, gs * b.w);
    unsigned lo = pk4(sa), hi = pk4(sb);
    return (long)(((unsigned long)hi << 32) | (unsigned long)lo);
}

static __device__ __forceinline__ void glds16(const void* g, void* l) {
    __builtin_amdgcn_global_load_lds(
        (const __attribute__((address_space(1))) void*)g,
        (__attribute__((address_space(3))) void*)l, 16, 0, 0);
}

// ---- prep: queue -> fp8, fragment-tiled (rows >= 375 zeroed) ----
__global__ void pgc_prep(const float* __restrict__ queue,
                         unsigned long long* __restrict__ qt)
{
    int u = blockIdx.x * 256 + threadIdx.x;      // 0..6143
    if (u >= 6144) return;
    int l = u & 63, ks = (u >> 6) & 3, nt = u >> 8;
    int row = nt * 16 + (l & 15);
    int k0 = (l >> 4) * 32 + ks * 8;
    float4 a = make_float4(0.f, 0.f, 0.f, 0.f);
    float4 b = make_float4(0.f, 0.f, 0.f, 0.f);
    if (row < NQ) {
        const float* p = queue + row * D + k0;
        a = *(const float4*)p;
        b = *(const float4*)(p + 4);
    }
    unsigned lo = pk4(a), hi = pk4(b);
    qt[u] = ((unsigned long long)hi << 32) | (unsigned long long)lo;
}

// ---- prepQ: class sums into pad rows 375..377 ----
__global__ void pgc_prep_qsum(const float* __restrict__ queue,
                              unsigned char* __restrict__ qtb)
{
    int c = blockIdx.x;          // 0..2
    int d = threadIdx.x;         // 0..127
    float s = 0.f;
    const float* p = queue + (long)c * QS * D + d;
    for (int r = 0; r < QS; ++r) s += p[r * D];
    int lg = d >> 5, ks = (d >> 3) & 3, j = d & 7;
    int u = 23 * 256 + ks * 64 + lg * 16 + 7 + c;    // tile 23, lr = 7+c
    qtb[u * 8 + j] = pk1(s);
}

// ---- main ----
__global__ __launch_bounds__(512, 4) void pgc_main(
    const float* __restrict__ act,
    const float* __restrict__ ema,
    const float* __restrict__ plab,
    const float* __restrict__ mask,
    const unsigned long long* __restrict__ qt,
    float* __restrict__ partial,
    int B)
{
    __shared__ unsigned long long qt_lds[6144];      // 49152 B
    __shared__ float s_red[8];

    const int tid = threadIdx.x;
    const int w   = tid >> 6;      // 0..7
    const int l   = tid & 63;
    const int lr  = l & 15;        // own sample row / C col
    const int seg = l >> 4;        // k-segment / C row group
    const long base0 = (long)blockIdx.x * 256 + w * 16;        // chunk 0
    const long base1 = base0 + 128;                            // chunk 1

    // ---- stage qt -> LDS: 6 glds/thread, fire-and-forget ----
    #pragma unroll
    for (int i = 0; i < 6; ++i) {
        glds16((const char*)qt + i * 8192 + w * 1024 + l * 16,
               (char*)qt_lds + i * 8192 + w * 1024);
    }

    // ================= chunk-0 loads =================
    long g0 = base0 + lr;
    const bool v0 = g0 < (long)B;
    const long r0 = v0 ? g0 : (long)B - 1;
    const float4* ap0 = (const float4*)(act + r0 * D) + seg * 8;
    const float4* ep0 = (const float4*)(ema + r0 * D) + seg * 8;
    float4 av[8], ev[8];
    #pragma unroll
    for (int i = 0; i < 8; ++i) av[i] = ap0[i];
    #pragma unroll
    for (int i = 0; i < 8; ++i) ev[i] = ep0[i];
    float mk0_raw = mask[r0];
    const float* pp0 = plab + r0 * 3;
    float q00 = pp0[0], q01 = pp0[1], q02 = pp0[2];
    __builtin_amdgcn_sched_barrier(0);

    // ---- consume chunk 0 -> af0, def2_0, scalars ----
    float ssa = 0.f;
    #pragma unroll
    for (int i = 0; i < 8; ++i)
        ssa += av[i].x*av[i].x + av[i].y*av[i].y + av[i].z*av[i].z + av[i].w*av[i].w;
    ssa += __shfl_xor(ssa, 16); ssa += __shfl_xor(ssa, 32);
    float inva = 1.0f / fmaxf(sqrtf(ssa), 1e-12f);
    float gsc  = 2.0f * inva;

    long af0[4];
    #pragma unroll
    for (int ks = 0; ks < 4; ++ks)
        af0[ks] = pk8(gsc, av[2 * ks], av[2 * ks + 1]);

    float sse = 0.f, dae = 0.f;
    #pragma unroll
    for (int i = 0; i < 8; ++i) {
        sse += ev[i].x*ev[i].x + ev[i].y*ev[i].y + ev[i].z*ev[i].z + ev[i].w*ev[i].w;
        dae += av[i].x*ev[i].x + av[i].y*ev[i].y + av[i].z*ev[i].z + av[i].w*ev[i].w;
    }
    sse += __shfl_xor(sse, 16); sse += __shfl_xor(sse, 32);
    dae += __shfl_xor(dae, 16); dae += __shfl_xor(dae, 32);
    float def2_0 = 2.0f * dae * inva * (1.0f / fmaxf(sqrtf(sse), 1e-12f));
    float mk0 = v0 ? mk0_raw : 0.f;
    int lb0 = 0; { float bst = q00;
        if (q01 > bst) { bst = q01; lb0 = 1; }
        if (q02 > bst) { lb0 = 2; } }

    __syncthreads();   // drains glds -> qt_lds ready

    // ================= issue chunk-1 loads (stay in flight) =================
    long g1 = base1 + lr;
    const bool v1 = g1 < (long)B;
    const long r1 = v1 ? g1 : (long)B - 1;
    const float4* ap1 = (const float4*)(act + r1 * D) + seg * 8;
    const float4* ep1 = (const float4*)(ema + r1 * D) + seg * 8;
    float4 av1[8], ev1[8];
    #pragma unroll
    for (int i = 0; i < 8; ++i) av1[i] = ap1[i];
    #pragma unroll
    for (int i = 0; i < 8; ++i) ev1[i] = ep1[i];
    float mk1_raw = mask[r1];
    const float* pp1 = plab + r1 * 3;
    float q10 = pp1[0], q11 = pp1[1], q12 = pp1[2];
    __builtin_amdgcn_sched_barrier(0);
    // first USE of av1/ev1 is after chunk-0's MFMA loop -> waitcnt lands there

    // ---- per-chunk MFMA loop + epilogue (R16 form) ----
    auto run_chunk = [&](const long* af, float def2, float mk, int lb) -> float {
        float S1[4] = {0.f, 0.f, 0.f, 0.f};
        f32x4 a23 = {0.f, 0.f, 0.f, 0.f};
        #pragma unroll
        for (int nt = 0; nt < 24; ++nt) {
            long b0 = (long)qt_lds[nt * 256 +       l];
            long b1 = (long)qt_lds[nt * 256 +  64 + l];
            long b2 = (long)qt_lds[nt * 256 + 128 + l];
            long b3 = (long)qt_lds[nt * 256 + 192 + l];
            f32x4 acc = {0.f, 0.f, 0.f, 0.f};
            acc = __builtin_amdgcn_mfma_f32_16x16x32_fp8_fp8(af[0], b0, acc, 0, 0, 0);
            acc = __builtin_amdgcn_mfma_f32_16x16x32_fp8_fp8(af[1], b1, acc, 0, 0, 0);
            acc = __builtin_amdgcn_mfma_f32_16x16x32_fp8_fp8(af[2], b2, acc, 0, 0, 0);
            acc = __builtin_amdgcn_mfma_f32_16x16x32_fp8_fp8(af[3], b3, acc, 0, 0, 0);
            if (nt < 23) {
                #pragma unroll
                for (int r = 0; r < 4; ++r)
                    S1[r] += __expf(acc[r]);
            } else {
                a23 = acc;
                if (lr < 7) {
                    #pragma unroll
                    for (int r = 0; r < 4; ++r)
                        S1[r] += __expf(acc[r]);
                }
            }
        }
        #pragma unroll
        for (int r = 0; r < 4; ++r) {
            S1[r] += __shfl_xor(S1[r], 1);
            S1[r] += __shfl_xor(S1[r], 2);
            S1[r] += __shfl_xor(S1[r], 4);
            S1[r] += __shfl_xor(S1[r], 8);
        }
        float c = 0.f;
        #pragma unroll
        for (int r = 0; r < 4; ++r) {
            const int m   = seg * 4 + r;
            const int lbm = __shfl(lb, m);
            const float S2 = __shfl(a23[r], (l & 48) + 7 + lbm);
            const float d2 = __shfl(def2, m);
            const float mm = __shfl(mk, m);
            const float denom = __expf(d2) + S1[r];
            const float per = __logf(denom) - (S2 + d2) * INV126;
            if (lr == 0) c += mm * per;
        }
        return c;
    };

    float ctot = run_chunk(af0, def2_0, mk0, lb0);

    // ---- consume chunk 1 (loads have been in flight for the whole loop) ----
    float ssa1 = 0.f;
    #pragma unroll
    for (int i = 0; i < 8; ++i)
        ssa1 += av1[i].x*av1[i].x + av1[i].y*av1[i].y + av1[i].z*av1[i].z + av1[i].w*av1[i].w;
    ssa1 += __shfl_xor(ssa1, 16); ssa1 += __shfl_xor(ssa1, 32);
    float inva1 = 1.0f / fmaxf(sqrtf(ssa1), 1e-12f);
    float gsc1  = 2.0f * inva1;

    long af1[4];
    #pragma unroll
    for (int ks = 0; ks < 4; ++ks)
        af1[ks] = pk8(gsc1, av1[2 * ks], av1[2 * ks + 1]);

    float sse1 = 0.f, dae1 = 0.f;
    #pragma unroll
    for (int i = 0; i < 8; ++i) {
        sse1 += ev1[i].x*ev1[i].x + ev1[i].y*ev1[i].y + ev1[i].z*ev1[i].z + ev1[i].w*ev1[i].w;
        dae1 += av1[i].x*ev1[i].x + av1[i].y*ev1[i].y + av1[i].z*ev1[i].z + av1[i].w*ev1[i].w;
    }
    sse1 += __shfl_xor(sse1, 16); sse1 += __shfl_xor(sse1, 32);
    dae1 += __shfl_xor(dae1, 16); dae1 += __shfl_xor(dae1, 32);
    float def2_1 = 2.0f * dae1 * inva1 * (1.0f / fmaxf(sqrtf(sse1), 1e-12f));
    float mk1 = v1 ? mk1_raw : 0.f;
    int lb1 = 0; { float bst = q10;
        if (q11 > bst) { bst = q11; lb1 = 1; }
        if (q12 > bst) { lb1 = 2; } }

    ctot += run_chunk(af1, def2_1, mk1, lb1);

    // ---- block reduce ----
    ctot += __shfl_xor(ctot, 16);
    ctot += __shfl_xor(ctot, 32);
    if (l == 0) s_red[w] = ctot;
    __syncthreads();
    if (w == 0) {
        float v = (l < 8) ? s_red[l] : 0.f;
        v += __shfl_xor(v, 1); v += __shfl_xor(v, 2); v += __shfl_xor(v, 4);
        if (l == 0) partial[blockIdx.x] = v;
    }
}

// ---- finish: deterministic tree reduce ----
__global__ void pgc_finish(const float* __restrict__ partial,
                           float* __restrict__ out, int n, float invB)
{
    __shared__ float r[4];
    const int tid = threadIdx.x;
    float s = 0.f;
    for (int i = tid; i < n; i += 256) s += partial[i];
    s += __shfl_xor(s, 1);  s += __shfl_xor(s, 2);
    s += __shfl_xor(s, 4);  s += __shfl_xor(s, 8);
    s += __shfl_xor(s, 16); s += __shfl_xor(s, 32);
    if ((tid & 63) == 0) r[tid >> 6] = s;
    __syncthreads();
    if (tid == 0) out[0] = (r[0] + r[1] + r[2] + r[3]) * invB;
}

extern "C" void kernel_launch(void* const* d_in, const int* in_sizes, int n_in,
                              void* d_out, int out_size, void* d_ws, size_t ws_size,
                              hipStream_t stream)
{
    const float* act   = (const float*)d_in[0];
    const float* ema   = (const float*)d_in[1];
    const float* plab  = (const float*)d_in[2];
    const float* mask  = (const float*)d_in[3];
    const float* queue = (const float*)d_in[4];
    float* out = (float*)d_out;

    const int B = in_sizes[0] / D;

    unsigned long long* qt = (unsigned long long*)d_ws;
    float* partial = (float*)((char*)d_ws + QT_BYTES);

    pgc_prep<<<24, 256, 0, stream>>>(queue, qt);
    pgc_prep_qsum<<<3, 128, 0, stream>>>(queue, (unsigned char*)d_ws);

    const int grid = (B + 255) / 256;        // 512 for B=131072
    pgc_main<<<grid, 512, 0, stream>>>(act, ema, plab, mask, qt, partial, B);

    pgc_finish<<<1, 256, 0, stream>>>(partial, out, grid, 1.0f / (float)B);
}

// Round 20
// 59.403 us; speedup vs baseline: 2.5847x; 2.5847x over previous
//
#include <hip/hip_runtime.h>
#include <math.h>

// PseudoGroupContrast — SPLIT design: streaming pass + compute pass.
//
//   R8-R19 lesson: one kernel that both streams 134MB and runs a long MFMA
//   loop per wave either spills (R17: 64MB, R19: 230MB scratch) or gets
//   register-minimized into serial HBM latency (VGPR=40-64, all pipes idle,
//   warm==cold). Split instead:
//
//   pgc_rows (A): pure streaming. act+ema -> norms, def2, label, mask ->
//     af fp8 in MFMA-fragment layout (afb[row*16+seg*4+ks]) + rowmeta
//     {def2, mk, lb}. No LDS/MFMA/barrier -> ~100% memory duty cycle ->
//     BW-bound by construction.
//   pgc_mm (B): R16's proven qt-in-LDS loop; global reads only af (32B/thr)
//     + meta (16B) -> serial head gone. Tile 23: lr<7 -> S1; lanes 7..9
//     carry S2 per class. per = log(exp(def2)+S1) - (S2+def2)/126.
//   prep/prepQ/finish as before (fp8-tiled queue + class sums + reduce).

#define D       128
#define NQ      375
#define QS      125
#define INV126  (1.0f/126.0f)
#define QT_BYTES 49152

typedef __attribute__((ext_vector_type(4))) float f32x4;

#if defined(__has_builtin)
#if __has_builtin(__builtin_amdgcn_cvt_pk_fp8_f32)
#define HAVE_CVT_FP8 1
#endif
#endif

#ifndef HAVE_CVT_FP8
static __device__ __forceinline__ unsigned f2e4m3_sw(float x) {
    unsigned u = __float_as_uint(x);
    unsigned s = (u >> 24) & 0x80;
    int e = (int)((u >> 23) & 0xFF);
    unsigned m = u & 0x7FFFFF;
    if (e == 0) return s;
    int te = e - 120;
    unsigned val;
    if (te >= 1) {
        unsigned keep = m >> 20;
        unsigned rest = m & 0xFFFFF;
        keep += (rest > 0x80000) || (rest == 0x80000 && (keep & 1));
        if (keep == 8) { keep = 0; te += 1; }
        val = (te >= 16) ? 0x7E : ((unsigned)(te << 3) | keep);
    } else {
        unsigned full = m | 0x800000;
        int sh = 21 - te;
        if (sh > 31) val = 0;
        else {
            unsigned keep = full >> sh;
            unsigned rem = full & ((1u << sh) - 1);
            unsigned half = 1u << (sh - 1);
            keep += (rem > half) || (rem == half && (keep & 1));
            val = keep;
        }
    }
    return s | val;
}
#endif

static __device__ __forceinline__ unsigned pk4(float4 v) {
#ifdef HAVE_CVT_FP8
    int r = __builtin_amdgcn_cvt_pk_fp8_f32(v.x, v.y, 0, false);
    r = __builtin_amdgcn_cvt_pk_fp8_f32(v.z, v.w, r, true);
    return (unsigned)r;
#else
    return f2e4m3_sw(v.x) | (f2e4m3_sw(v.y) << 8)
         | (f2e4m3_sw(v.z) << 16) | (f2e4m3_sw(v.w) << 24);
#endif
}

static __device__ __forceinline__ unsigned char pk1(float x) {
#ifdef HAVE_CVT_FP8
    return (unsigned char)(__builtin_amdgcn_cvt_pk_fp8_f32(x, x, 0, false) & 0xff);
#else
    return (unsigned char)f2e4m3_sw(x);
#endif
}

static __device__ __forceinline__ unsigned long long pk8u(float gs, float4 a, float4 b) {
    float4 sa = make_float4(gs * a.x, gs * a.y, gs * a.z, gs * a.w);
    float4 sb = make_float4(gs * b.x, gs * b.y, gs * b.z, gs * b.w);
    unsigned lo = pk4(sa), hi = pk4(sb);
    return ((unsigned long long)hi << 32) | (unsigned long long)lo;
}

static __device__ __forceinline__ void glds16(const void* g, void* l) {
    __builtin_amdgcn_global_load_lds(
        (const __attribute__((address_space(1))) void*)g,
        (__attribute__((address_space(3))) void*)l, 16, 0, 0);
}

// ---- prep: queue -> fp8, fragment-tiled (rows >= 375 zeroed) ----
__global__ void pgc_prep(const float* __restrict__ queue,
                         unsigned long long* __restrict__ qt)
{
    int u = blockIdx.x * 256 + threadIdx.x;      // 0..6143
    if (u >= 6144) return;
    int l = u & 63, ks = (u >> 6) & 3, nt = u >> 8;
    int row = nt * 16 + (l & 15);
    int k0 = (l >> 4) * 32 + ks * 8;
    float4 a = make_float4(0.f, 0.f, 0.f, 0.f);
    float4 b = make_float4(0.f, 0.f, 0.f, 0.f);
    if (row < NQ) {
        const float* p = queue + row * D + k0;
        a = *(const float4*)p;
        b = *(const float4*)(p + 4);
    }
    unsigned lo = pk4(a), hi = pk4(b);
    qt[u] = ((unsigned long long)hi << 32) | (unsigned long long)lo;
}

// ---- prepQ: class sums into pad rows 375..377 (tile 23, lr=7..9) ----
__global__ void pgc_prep_qsum(const float* __restrict__ queue,
                              unsigned char* __restrict__ qtb)
{
    int c = blockIdx.x;          // 0..2
    int d = threadIdx.x;         // 0..127
    float s = 0.f;
    const float* p = queue + (long)c * QS * D + d;
    for (int r = 0; r < QS; ++r) s += p[r * D];
    int lg = d >> 5, ks = (d >> 3) & 3, j = d & 7;
    int u = 23 * 256 + ks * 64 + lg * 16 + 7 + c;
    qtb[u * 8 + j] = pk1(s);
}

// ---- A: pure streaming row pass ----
__global__ __launch_bounds__(256, 4) void pgc_rows(
    const float* __restrict__ act,
    const float* __restrict__ ema,
    const float* __restrict__ plab,
    const float* __restrict__ mask,
    unsigned long long* __restrict__ afb,   // [row*16 + seg*4 + ks]
    float4* __restrict__ rowmeta,           // {def2, mk, lb, 0}
    int B)
{
    const int tid = threadIdx.x;
    const int w   = tid >> 6;
    const int l   = tid & 63;
    const int lr  = l & 15;
    const int seg = l >> 4;

    const long grow  = (long)blockIdx.x * 64 + w * 16 + lr;
    const bool valid = grow < (long)B;
    const long gr    = valid ? grow : (long)B - 1;

    const float4* ap = (const float4*)(act + gr * D) + seg * 8;
    const float4* ep = (const float4*)(ema + gr * D) + seg * 8;

    float4 av[8], ev[8];
    #pragma unroll
    for (int i = 0; i < 8; ++i) av[i] = ap[i];
    #pragma unroll
    for (int i = 0; i < 8; ++i) ev[i] = ep[i];
    float mk_raw = mask[gr];
    const float* pp = plab + gr * 3;
    float p0 = pp[0], p1 = pp[1], p2 = pp[2];
    __builtin_amdgcn_sched_barrier(0);

    float ssa = 0.f, sse = 0.f, dae = 0.f;
    #pragma unroll
    for (int i = 0; i < 8; ++i) {
        ssa += av[i].x*av[i].x + av[i].y*av[i].y + av[i].z*av[i].z + av[i].w*av[i].w;
        sse += ev[i].x*ev[i].x + ev[i].y*ev[i].y + ev[i].z*ev[i].z + ev[i].w*ev[i].w;
        dae += av[i].x*ev[i].x + av[i].y*ev[i].y + av[i].z*ev[i].z + av[i].w*ev[i].w;
    }
    ssa += __shfl_xor(ssa, 16); ssa += __shfl_xor(ssa, 32);
    sse += __shfl_xor(sse, 16); sse += __shfl_xor(sse, 32);
    dae += __shfl_xor(dae, 16); dae += __shfl_xor(dae, 32);

    const float inva = 1.0f / fmaxf(sqrtf(ssa), 1e-12f);
    const float inve = 1.0f / fmaxf(sqrtf(sse), 1e-12f);
    const float gs   = 2.0f * inva;                  // fold 1/T + norm into A

    unsigned long long a0 = pk8u(gs, av[0], av[1]);
    unsigned long long a1 = pk8u(gs, av[2], av[3]);
    unsigned long long a2 = pk8u(gs, av[4], av[5]);
    unsigned long long a3 = pk8u(gs, av[6], av[7]);

    if (valid) {
        unsigned long long* dst = afb + grow * 16 + seg * 4;
        dst[0] = a0; dst[1] = a1; dst[2] = a2; dst[3] = a3;
        if (seg == 0) {
            int lb = 0; float bst = p0;
            if (p1 > bst) { bst = p1; lb = 1; }      // first-max = argmax
            if (p2 > bst) { lb = 2; }
            rowmeta[grow] = make_float4(2.0f * dae * inva * inve,
                                        mk_raw, (float)lb, 0.f);
        }
    }
}

// ---- B: qt-in-LDS MFMA pass (R16 proven loop) ----
__global__ __launch_bounds__(512, 4) void pgc_mm(
    const unsigned long long* __restrict__ afb,
    const float4* __restrict__ rowmeta,
    const unsigned long long* __restrict__ qt,
    float* __restrict__ partial,
    int B)
{
    __shared__ unsigned long long qt_lds[6144];      // 49152 B
    __shared__ float s_red[8];

    const int tid = threadIdx.x;
    const int w   = tid >> 6;      // 0..7
    const int l   = tid & 63;
    const int lr  = l & 15;
    const int seg = l >> 4;
    const long rowbase = (long)blockIdx.x * 128 + w * 16;

    // ---- stage qt -> LDS: 6 glds/thread, fire-and-forget ----
    #pragma unroll
    for (int i = 0; i < 6; ++i) {
        glds16((const char*)qt + i * 8192 + w * 1024 + l * 16,
               (char*)qt_lds + i * 8192 + w * 1024);
    }

    // ---- tiny global reads: af fragments (32B) + own-row meta (16B) ----
    long grow = rowbase + lr;
    const bool valid = grow < (long)B;
    const long gr = valid ? grow : (long)B - 1;

    const unsigned long long* ap = afb + gr * 16 + seg * 4;
    long af[4];
    af[0] = (long)ap[0]; af[1] = (long)ap[1];
    af[2] = (long)ap[2]; af[3] = (long)ap[3];
    float4 meta = rowmeta[gr];
    const float def2 = meta.x;
    const float mk   = valid ? meta.y : 0.f;
    const int   lb   = (int)meta.z;

    __syncthreads();   // drains glds -> qt_lds ready

    // ---- 24-tile fp8 MFMA loop (R16 form) ----
    float S1[4] = {0.f, 0.f, 0.f, 0.f};
    f32x4 a23 = {0.f, 0.f, 0.f, 0.f};
    #pragma unroll
    for (int nt = 0; nt < 24; ++nt) {
        long b0 = (long)qt_lds[nt * 256 +       l];
        long b1 = (long)qt_lds[nt * 256 +  64 + l];
        long b2 = (long)qt_lds[nt * 256 + 128 + l];
        long b3 = (long)qt_lds[nt * 256 + 192 + l];
        f32x4 acc = {0.f, 0.f, 0.f, 0.f};
        acc = __builtin_amdgcn_mfma_f32_16x16x32_fp8_fp8(af[0], b0, acc, 0, 0, 0);
        acc = __builtin_amdgcn_mfma_f32_16x16x32_fp8_fp8(af[1], b1, acc, 0, 0, 0);
        acc = __builtin_amdgcn_mfma_f32_16x16x32_fp8_fp8(af[2], b2, acc, 0, 0, 0);
        acc = __builtin_amdgcn_mfma_f32_16x16x32_fp8_fp8(af[3], b3, acc, 0, 0, 0);
        if (nt < 23) {
            #pragma unroll
            for (int r = 0; r < 4; ++r)
                S1[r] += __expf(acc[r]);
        } else {
            a23 = acc;                 // lanes 7..9 hold class S2; lr<7 real
            if (lr < 7) {
                #pragma unroll
                for (int r = 0; r < 4; ++r)
                    S1[r] += __expf(acc[r]);
            }
        }
    }

    // ---- reduce S1 over the 16 column lanes ----
    #pragma unroll
    for (int r = 0; r < 4; ++r) {
        S1[r] += __shfl_xor(S1[r], 1);
        S1[r] += __shfl_xor(S1[r], 2);
        S1[r] += __shfl_xor(S1[r], 4);
        S1[r] += __shfl_xor(S1[r], 8);
    }

    // ---- epilogue: S2 via variable-lane shuffle from tile-23 acc ----
    float c = 0.f;
    #pragma unroll
    for (int r = 0; r < 4; ++r) {
        const int m   = seg * 4 + r;
        const int lbm = __shfl(lb, m);
        const float S2 = __shfl(a23[r], (l & 48) + 7 + lbm);
        const float d2 = __shfl(def2, m);
        const float mm = __shfl(mk, m);
        const float denom = __expf(d2) + S1[r];
        const float per = __logf(denom) - (S2 + d2) * INV126;
        if (lr == 0) c += mm * per;
    }
    c += __shfl_xor(c, 16);
    c += __shfl_xor(c, 32);
    if (l == 0) s_red[w] = c;
    __syncthreads();
    if (w == 0) {
        float v = (l < 8) ? s_red[l] : 0.f;
        v += __shfl_xor(v, 1); v += __shfl_xor(v, 2); v += __shfl_xor(v, 4);
        if (l == 0) partial[blockIdx.x] = v;
    }
}

// ---- finish: deterministic tree reduce ----
__global__ void pgc_finish(const float* __restrict__ partial,
                           float* __restrict__ out, int n, float invB)
{
    __shared__ float r[4];
    const int tid = threadIdx.x;
    float s = 0.f;
    for (int i = tid; i < n; i += 256) s += partial[i];
    s += __shfl_xor(s, 1);  s += __shfl_xor(s, 2);
    s += __shfl_xor(s, 4);  s += __shfl_xor(s, 8);
    s += __shfl_xor(s, 16); s += __shfl_xor(s, 32);
    if ((tid & 63) == 0) r[tid >> 6] = s;
    __syncthreads();
    if (tid == 0) out[0] = (r[0] + r[1] + r[2] + r[3]) * invB;
}

extern "C" void kernel_launch(void* const* d_in, const int* in_sizes, int n_in,
                              void* d_out, int out_size, void* d_ws, size_t ws_size,
                              hipStream_t stream)
{
    const float* act   = (const float*)d_in[0];
    const float* ema   = (const float*)d_in[1];
    const float* plab  = (const float*)d_in[2];
    const float* mask  = (const float*)d_in[3];
    const float* queue = (const float*)d_in[4];
    float* out = (float*)d_out;

    const int B = in_sizes[0] / D;
    const long Brnd = ((long)B + 255) & ~255L;

    // ws layout: qt 48KB | partial 16KB | rowmeta 16B*Brnd | afb 128B*Brnd
    unsigned long long* qt = (unsigned long long*)d_ws;
    float* partial = (float*)((char*)d_ws + QT_BYTES);
    float4* rowmeta = (float4*)((char*)d_ws + QT_BYTES + 16384);
    unsigned long long* afb =
        (unsigned long long*)((char*)d_ws + QT_BYTES + 16384 + Brnd * 16);

    pgc_prep<<<24, 256, 0, stream>>>(queue, qt);
    pgc_prep_qsum<<<3, 128, 0, stream>>>(queue, (unsigned char*)d_ws);

    const int gridA = (B + 63) / 64;         // 2048
    pgc_rows<<<gridA, 256, 0, stream>>>(act, ema, plab, mask, afb, rowmeta, B);

    const int gridB = (B + 127) / 128;       // 1024
    pgc_mm<<<gridB, 512, 0, stream>>>(afb, rowmeta, qt, partial, B);

    pgc_finish<<<1, 256, 0, stream>>>(partial, out, gridB, 1.0f / (float)B);
}

// Round 21
// 56.651 us; speedup vs baseline: 2.7103x; 1.0486x over previous
//
#include <hip/hip_runtime.h>
#include <math.h>

// PseudoGroupContrast — SPLIT design v2: fine-grained streaming pass.
//
//   R20 evidence: mm+preps ≈ 9 µs; rows = 50 µs at 1.75 TB/s, VGPR=36 —
//   16 loads/thread with ~2 in flight = 8 serial HBM rounds/wave. The
//   allocator always picks minimal VGPR, so make minimal VGPR sufficient:
//   16 threads/row x 2 float4 per array -> per-thread chain of 4 loads
//   (16 VGPRs of results), 4x the waves (32K), ~2 load-rounds/wave.
//   In-flight/CU ≈ 32 waves x 4KB >> 25KB Little's-law -> BW-bound.
//
//   pgc_rows (A): act+ema -> norms, def2, label, mask -> af fp8 fragments
//     (afb[row*16+s], s = 8-float slice = fragment index) + rowmeta.
//   pgc_mm (B): qt-in-LDS MFMA loop (R16 proven); reads af 32B/thr.
//     Tile 23: lr<7 -> S1; lanes 7..9 carry S2 per class.
//     per = log(exp(def2)+S1) - (S2+def2)/126,  def2 = 2*f_hat.ef_hat
//   prep/prepQ/finish unchanged.

#define D       128
#define NQ      375
#define QS      125
#define INV126  (1.0f/126.0f)
#define QT_BYTES 49152

typedef __attribute__((ext_vector_type(4))) float f32x4;

#if defined(__has_builtin)
#if __has_builtin(__builtin_amdgcn_cvt_pk_fp8_f32)
#define HAVE_CVT_FP8 1
#endif
#endif

#ifndef HAVE_CVT_FP8
static __device__ __forceinline__ unsigned f2e4m3_sw(float x) {
    unsigned u = __float_as_uint(x);
    unsigned s = (u >> 24) & 0x80;
    int e = (int)((u >> 23) & 0xFF);
    unsigned m = u & 0x7FFFFF;
    if (e == 0) return s;
    int te = e - 120;
    unsigned val;
    if (te >= 1) {
        unsigned keep = m >> 20;
        unsigned rest = m & 0xFFFFF;
        keep += (rest > 0x80000) || (rest == 0x80000 && (keep & 1));
        if (keep == 8) { keep = 0; te += 1; }
        val = (te >= 16) ? 0x7E : ((unsigned)(te << 3) | keep);
    } else {
        unsigned full = m | 0x800000;
        int sh = 21 - te;
        if (sh > 31) val = 0;
        else {
            unsigned keep = full >> sh;
            unsigned rem = full & ((1u << sh) - 1);
            unsigned half = 1u << (sh - 1);
            keep += (rem > half) || (rem == half && (keep & 1));
            val = keep;
        }
    }
    return s | val;
}
#endif

static __device__ __forceinline__ unsigned pk4(float4 v) {
#ifdef HAVE_CVT_FP8
    int r = __builtin_amdgcn_cvt_pk_fp8_f32(v.x, v.y, 0, false);
    r = __builtin_amdgcn_cvt_pk_fp8_f32(v.z, v.w, r, true);
    return (unsigned)r;
#else
    return f2e4m3_sw(v.x) | (f2e4m3_sw(v.y) << 8)
         | (f2e4m3_sw(v.z) << 16) | (f2e4m3_sw(v.w) << 24);
#endif
}

static __device__ __forceinline__ unsigned char pk1(float x) {
#ifdef HAVE_CVT_FP8
    return (unsigned char)(__builtin_amdgcn_cvt_pk_fp8_f32(x, x, 0, false) & 0xff);
#else
    return (unsigned char)f2e4m3_sw(x);
#endif
}

static __device__ __forceinline__ void glds16(const void* g, void* l) {
    __builtin_amdgcn_global_load_lds(
        (const __attribute__((address_space(1))) void*)g,
        (__attribute__((address_space(3))) void*)l, 16, 0, 0);
}

// ---- prep: queue -> fp8, fragment-tiled (rows >= 375 zeroed) ----
__global__ void pgc_prep(const float* __restrict__ queue,
                         unsigned long long* __restrict__ qt)
{
    int u = blockIdx.x * 256 + threadIdx.x;      // 0..6143
    if (u >= 6144) return;
    int l = u & 63, ks = (u >> 6) & 3, nt = u >> 8;
    int row = nt * 16 + (l & 15);
    int k0 = (l >> 4) * 32 + ks * 8;
    float4 a = make_float4(0.f, 0.f, 0.f, 0.f);
    float4 b = make_float4(0.f, 0.f, 0.f, 0.f);
    if (row < NQ) {
        const float* p = queue + row * D + k0;
        a = *(const float4*)p;
        b = *(const float4*)(p + 4);
    }
    unsigned lo = pk4(a), hi = pk4(b);
    qt[u] = ((unsigned long long)hi << 32) | (unsigned long long)lo;
}

// ---- prepQ: class sums into pad rows 375..377 (tile 23, lr=7..9) ----
__global__ void pgc_prep_qsum(const float* __restrict__ queue,
                              unsigned char* __restrict__ qtb)
{
    int c = blockIdx.x;          // 0..2
    int d = threadIdx.x;         // 0..127
    float s = 0.f;
    const float* p = queue + (long)c * QS * D + d;
    for (int r = 0; r < QS; ++r) s += p[r * D];
    int lg = d >> 5, ks = (d >> 3) & 3, j = d & 7;
    int u = 23 * 256 + ks * 64 + lg * 16 + 7 + c;
    qtb[u * 8 + j] = pk1(s);
}

// ---- A: fine-grained streaming row pass (16 threads/row) ----
__global__ __launch_bounds__(256, 8) void pgc_rows(
    const float* __restrict__ act,
    const float* __restrict__ ema,
    const float* __restrict__ plab,
    const float* __restrict__ mask,
    unsigned long long* __restrict__ afb,   // [row*16 + s], s = 8-float slice
    float4* __restrict__ rowmeta,           // {def2, mk, lb, 0}
    int B)
{
    const int tid = threadIdx.x;
    const int s   = tid & 15;               // slice: floats [s*8, s*8+8)
    const long row = (long)blockIdx.x * 16 + (tid >> 4);
    const bool valid = row < (long)B;
    const long gr = valid ? row : (long)B - 1;

    // 4 loads/thread: short chain, fits minimal-VGPR schedules
    const float4* ap = (const float4*)(act + gr * D) + s * 2;
    const float4* ep = (const float4*)(ema + gr * D) + s * 2;
    float4 a0 = ap[0], a1 = ap[1];
    float4 e0 = ep[0], e1 = ep[1];

    float mk_raw = 0.f, p0 = 0.f, p1 = 0.f, p2 = 0.f;
    if (s == 0) {
        mk_raw = mask[gr];
        const float* pp = plab + gr * 3;
        p0 = pp[0]; p1 = pp[1]; p2 = pp[2];
    }

    float ssa = a0.x*a0.x + a0.y*a0.y + a0.z*a0.z + a0.w*a0.w
              + a1.x*a1.x + a1.y*a1.y + a1.z*a1.z + a1.w*a1.w;
    float sse = e0.x*e0.x + e0.y*e0.y + e0.z*e0.z + e0.w*e0.w
              + e1.x*e1.x + e1.y*e1.y + e1.z*e1.z + e1.w*e1.w;
    float dae = a0.x*e0.x + a0.y*e0.y + a0.z*e0.z + a0.w*e0.w
              + a1.x*e1.x + a1.y*e1.y + a1.z*e1.z + a1.w*e1.w;

    // reduce across the 16 lanes of this row (xor < 16 stays in-group)
    ssa += __shfl_xor(ssa, 1); ssa += __shfl_xor(ssa, 2);
    ssa += __shfl_xor(ssa, 4); ssa += __shfl_xor(ssa, 8);
    sse += __shfl_xor(sse, 1); sse += __shfl_xor(sse, 2);
    sse += __shfl_xor(sse, 4); sse += __shfl_xor(sse, 8);
    dae += __shfl_xor(dae, 1); dae += __shfl_xor(dae, 2);
    dae += __shfl_xor(dae, 4); dae += __shfl_xor(dae, 8);

    const float inva = 1.0f / fmaxf(sqrtf(ssa), 1e-12f);
    const float inve = 1.0f / fmaxf(sqrtf(sse), 1e-12f);
    const float gs   = 2.0f * inva;         // fold 1/T + norm into A

    float4 sa = make_float4(gs*a0.x, gs*a0.y, gs*a0.z, gs*a0.w);
    float4 sb = make_float4(gs*a1.x, gs*a1.y, gs*a1.z, gs*a1.w);
    unsigned long long frag =
        ((unsigned long long)pk4(sb) << 32) | (unsigned long long)pk4(sa);

    if (valid) {
        afb[row * 16 + s] = frag;           // = blockbase*16 + tid: coalesced
        if (s == 0) {
            int lb = 0; float bst = p0;
            if (p1 > bst) { bst = p1; lb = 1; }   // first-max = argmax
            if (p2 > bst) { lb = 2; }
            rowmeta[row] = make_float4(2.0f * dae * inva * inve,
                                       mk_raw, (float)lb, 0.f);
        }
    }
}

// ---- B: qt-in-LDS MFMA pass (R16 proven loop) ----
__global__ __launch_bounds__(512, 4) void pgc_mm(
    const unsigned long long* __restrict__ afb,
    const float4* __restrict__ rowmeta,
    const unsigned long long* __restrict__ qt,
    float* __restrict__ partial,
    int B)
{
    __shared__ unsigned long long qt_lds[6144];      // 49152 B
    __shared__ float s_red[8];

    const int tid = threadIdx.x;
    const int w   = tid >> 6;      // 0..7
    const int l   = tid & 63;
    const int lr  = l & 15;
    const int seg = l >> 4;
    const long rowbase = (long)blockIdx.x * 128 + w * 16;

    // ---- stage qt -> LDS: 6 glds/thread, fire-and-forget ----
    #pragma unroll
    for (int i = 0; i < 6; ++i) {
        glds16((const char*)qt + i * 8192 + w * 1024 + l * 16,
               (char*)qt_lds + i * 8192 + w * 1024);
    }

    // ---- tiny global reads: af fragments (32B) + own-row meta (16B) ----
    long grow = rowbase + lr;
    const bool valid = grow < (long)B;
    const long gr = valid ? grow : (long)B - 1;

    const unsigned long long* ap = afb + gr * 16 + seg * 4;
    long af[4];
    af[0] = (long)ap[0]; af[1] = (long)ap[1];
    af[2] = (long)ap[2]; af[3] = (long)ap[3];
    float4 meta = rowmeta[gr];
    const float def2 = meta.x;
    const float mk   = valid ? meta.y : 0.f;
    const int   lb   = (int)meta.z;

    __syncthreads();   // drains glds -> qt_lds ready

    // ---- 24-tile fp8 MFMA loop (R16 form) ----
    float S1[4] = {0.f, 0.f, 0.f, 0.f};
    f32x4 a23 = {0.f, 0.f, 0.f, 0.f};
    #pragma unroll
    for (int nt = 0; nt < 24; ++nt) {
        long b0 = (long)qt_lds[nt * 256 +       l];
        long b1 = (long)qt_lds[nt * 256 +  64 + l];
        long b2 = (long)qt_lds[nt * 256 + 128 + l];
        long b3 = (long)qt_lds[nt * 256 + 192 + l];
        f32x4 acc = {0.f, 0.f, 0.f, 0.f};
        acc = __builtin_amdgcn_mfma_f32_16x16x32_fp8_fp8(af[0], b0, acc, 0, 0, 0);
        acc = __builtin_amdgcn_mfma_f32_16x16x32_fp8_fp8(af[1], b1, acc, 0, 0, 0);
        acc = __builtin_amdgcn_mfma_f32_16x16x32_fp8_fp8(af[2], b2, acc, 0, 0, 0);
        acc = __builtin_amdgcn_mfma_f32_16x16x32_fp8_fp8(af[3], b3, acc, 0, 0, 0);
        if (nt < 23) {
            #pragma unroll
            for (int r = 0; r < 4; ++r)
                S1[r] += __expf(acc[r]);
        } else {
            a23 = acc;                 // lanes 7..9 hold class S2; lr<7 real
            if (lr < 7) {
                #pragma unroll
                for (int r = 0; r < 4; ++r)
                    S1[r] += __expf(acc[r]);
            }
        }
    }

    // ---- reduce S1 over the 16 column lanes ----
    #pragma unroll
    for (int r = 0; r < 4; ++r) {
        S1[r] += __shfl_xor(S1[r], 1);
        S1[r] += __shfl_xor(S1[r], 2);
        S1[r] += __shfl_xor(S1[r], 4);
        S1[r] += __shfl_xor(S1[r], 8);
    }

    // ---- epilogue: S2 via variable-lane shuffle from tile-23 acc ----
    float c = 0.f;
    #pragma unroll
    for (int r = 0; r < 4; ++r) {
        const int m   = seg * 4 + r;
        const int lbm = __shfl(lb, m);
        const float S2 = __shfl(a23[r], (l & 48) + 7 + lbm);
        const float d2 = __shfl(def2, m);
        const float mm = __shfl(mk, m);
        const float denom = __expf(d2) + S1[r];
        const float per = __logf(denom) - (S2 + d2) * INV126;
        if (lr == 0) c += mm * per;
    }
    c += __shfl_xor(c, 16);
    c += __shfl_xor(c, 32);
    if (l == 0) s_red[w] = c;
    __syncthreads();
    if (w == 0) {
        float v = (l < 8) ? s_red[l] : 0.f;
        v += __shfl_xor(v, 1); v += __shfl_xor(v, 2); v += __shfl_xor(v, 4);
        if (l == 0) partial[blockIdx.x] = v;
    }
}

// ---- finish: deterministic tree reduce ----
__global__ void pgc_finish(const float* __restrict__ partial,
                           float* __restrict__ out, int n, float invB)
{
    __shared__ float r[4];
    const int tid = threadIdx.x;
    float s = 0.f;
    for (int i = tid; i < n; i += 256) s += partial[i];
    s += __shfl_xor(s, 1);  s += __shfl_xor(s, 2);
    s += __shfl_xor(s, 4);  s += __shfl_xor(s, 8);
    s += __shfl_xor(s, 16); s += __shfl_xor(s, 32);
    if ((tid & 63) == 0) r[tid >> 6] = s;
    __syncthreads();
    if (tid == 0) out[0] = (r[0] + r[1] + r[2] + r[3]) * invB;
}

extern "C" void kernel_launch(void* const* d_in, const int* in_sizes, int n_in,
                              void* d_out, int out_size, void* d_ws, size_t ws_size,
                              hipStream_t stream)
{
    const float* act   = (const float*)d_in[0];
    const float* ema   = (const float*)d_in[1];
    const float* plab  = (const float*)d_in[2];
    const float* mask  = (const float*)d_in[3];
    const float* queue = (const float*)d_in[4];
    float* out = (float*)d_out;

    const int B = in_sizes[0] / D;
    const long Brnd = ((long)B + 255) & ~255L;

    // ws layout: qt 48KB | partial 16KB | rowmeta 16B*Brnd | afb 128B*Brnd
    unsigned long long* qt = (unsigned long long*)d_ws;
    float* partial = (float*)((char*)d_ws + QT_BYTES);
    float4* rowmeta = (float4*)((char*)d_ws + QT_BYTES + 16384);
    unsigned long long* afb =
        (unsigned long long*)((char*)d_ws + QT_BYTES + 16384 + Brnd * 16);

    pgc_prep<<<24, 256, 0, stream>>>(queue, qt);
    pgc_prep_qsum<<<3, 128, 0, stream>>>(queue, (unsigned char*)d_ws);

    const int gridA = (B + 15) / 16;         // 8192
    pgc_rows<<<gridA, 256, 0, stream>>>(act, ema, plab, mask, afb, rowmeta, B);

    const int gridB = (B + 127) / 128;       // 1024
    pgc_mm<<<gridB, 512, 0, stream>>>(afb, rowmeta, qt, partial, B);

    pgc_finish<<<1, 256, 0, stream>>>(partial, out, gridB, 1.0f / (float)B);
}

// Round 22
// 56.466 us; speedup vs baseline: 2.7192x; 1.0033x over previous
//
#include <hip/hip_runtime.h>
#include <math.h>

// PseudoGroupContrast — SPLIT v3: request-rate-clean streaming pass.
//
//   R21 diagnosis: warm==cold at ~2 TB/s = sector-REQUEST-rate limited, not
//   byte limited. Cause: strided per-wave access (16B holes) in every rows
//   variant (R20: 512B stride; R21: 32B stride) -> 2x sector requests/byte.
//   m146's RMSNorm (contiguous 16B/lane + grid-stride) hits 4.89 TB/s.
//
//   pgc_rows (A): thread s loads float4 idx {s, s+16} of each row (wave
//     access = contiguous 256B chunks), grid-stride 8 rows/group. Fragment
//     regroup (floats [8u,8u+8) from lanes 2u,2u+1) via 4 shuffles after
//     fp8 pack. afb stores coalesced. rowmeta {def2, mk, lb}.
//   pgc_mm (B): qt-in-LDS MFMA loop (R16/R20 proven, ~9 µs with preps).
//     Tile 23: lr<7 -> S1; lanes 7..9 carry S2 per class.
//     per = log(exp(def2)+S1) - (S2+def2)/126,  def2 = 2*f_hat.ef_hat
//   prep/prepQ/finish unchanged.

#define D       128
#define NQ      375
#define QS      125
#define INV126  (1.0f/126.0f)
#define QT_BYTES 49152
#define RPB     128           // rows per block in pgc_rows (16 groups x 8 iter)

typedef __attribute__((ext_vector_type(4))) float f32x4;

#if defined(__has_builtin)
#if __has_builtin(__builtin_amdgcn_cvt_pk_fp8_f32)
#define HAVE_CVT_FP8 1
#endif
#endif

#ifndef HAVE_CVT_FP8
static __device__ __forceinline__ unsigned f2e4m3_sw(float x) {
    unsigned u = __float_as_uint(x);
    unsigned s = (u >> 24) & 0x80;
    int e = (int)((u >> 23) & 0xFF);
    unsigned m = u & 0x7FFFFF;
    if (e == 0) return s;
    int te = e - 120;
    unsigned val;
    if (te >= 1) {
        unsigned keep = m >> 20;
        unsigned rest = m & 0xFFFFF;
        keep += (rest > 0x80000) || (rest == 0x80000 && (keep & 1));
        if (keep == 8) { keep = 0; te += 1; }
        val = (te >= 16) ? 0x7E : ((unsigned)(te << 3) | keep);
    } else {
        unsigned full = m | 0x800000;
        int sh = 21 - te;
        if (sh > 31) val = 0;
        else {
            unsigned keep = full >> sh;
            unsigned rem = full & ((1u << sh) - 1);
            unsigned half = 1u << (sh - 1);
            keep += (rem > half) || (rem == half && (keep & 1));
            val = keep;
        }
    }
    return s | val;
}
#endif

static __device__ __forceinline__ unsigned pk4(float4 v) {
#ifdef HAVE_CVT_FP8
    int r = __builtin_amdgcn_cvt_pk_fp8_f32(v.x, v.y, 0, false);
    r = __builtin_amdgcn_cvt_pk_fp8_f32(v.z, v.w, r, true);
    return (unsigned)r;
#else
    return f2e4m3_sw(v.x) | (f2e4m3_sw(v.y) << 8)
         | (f2e4m3_sw(v.z) << 16) | (f2e4m3_sw(v.w) << 24);
#endif
}

static __device__ __forceinline__ unsigned char pk1(float x) {
#ifdef HAVE_CVT_FP8
    return (unsigned char)(__builtin_amdgcn_cvt_pk_fp8_f32(x, x, 0, false) & 0xff);
#else
    return (unsigned char)f2e4m3_sw(x);
#endif
}

static __device__ __forceinline__ void glds16(const void* g, void* l) {
    __builtin_amdgcn_global_load_lds(
        (const __attribute__((address_space(1))) void*)g,
        (__attribute__((address_space(3))) void*)l, 16, 0, 0);
}

// ---- prep: queue -> fp8, fragment-tiled (rows >= 375 zeroed) ----
__global__ void pgc_prep(const float* __restrict__ queue,
                         unsigned long long* __restrict__ qt)
{
    int u = blockIdx.x * 256 + threadIdx.x;      // 0..6143
    if (u >= 6144) return;
    int l = u & 63, ks = (u >> 6) & 3, nt = u >> 8;
    int row = nt * 16 + (l & 15);
    int k0 = (l >> 4) * 32 + ks * 8;
    float4 a = make_float4(0.f, 0.f, 0.f, 0.f);
    float4 b = make_float4(0.f, 0.f, 0.f, 0.f);
    if (row < NQ) {
        const float* p = queue + row * D + k0;
        a = *(const float4*)p;
        b = *(const float4*)(p + 4);
    }
    unsigned lo = pk4(a), hi = pk4(b);
    qt[u] = ((unsigned long long)hi << 32) | (unsigned long long)lo;
}

// ---- prepQ: class sums into pad rows 375..377 (tile 23, lr=7..9) ----
__global__ void pgc_prep_qsum(const float* __restrict__ queue,
                              unsigned char* __restrict__ qtb)
{
    int c = blockIdx.x;          // 0..2
    int d = threadIdx.x;         // 0..127
    float s = 0.f;
    const float* p = queue + (long)c * QS * D + d;
    for (int r = 0; r < QS; ++r) s += p[r * D];
    int lg = d >> 5, ks = (d >> 3) & 3, j = d & 7;
    int u = 23 * 256 + ks * 64 + lg * 16 + 7 + c;
    qtb[u * 8 + j] = pk1(s);
}

// ---- A: contiguous-access grid-stride streaming pass ----
__global__ __launch_bounds__(256, 8) void pgc_rows(
    const float* __restrict__ act,
    const float* __restrict__ ema,
    const float* __restrict__ plab,
    const float* __restrict__ mask,
    unsigned long long* __restrict__ afb,   // [row*16 + u]
    float4* __restrict__ rowmeta,           // {def2, mk, lb, 0}
    int B)
{
    const int tid = threadIdx.x;
    const int s   = tid & 15;               // slice within row
    const int grp = tid >> 4;               // row-group 0..15
    const int gl  = tid & 63;               // lane

    for (int it = 0; it < 8; ++it) {
        const long row = (long)blockIdx.x * RPB + it * 16 + grp;
        const bool valid = row < (long)B;
        const long gr = valid ? row : (long)B - 1;

        // contiguous wave access: float4 idx {s, s+16} per row (256B chunks)
        const float4* a4 = (const float4*)(act + gr * D);
        const float4* e4 = (const float4*)(ema + gr * D);
        float4 A0 = a4[s], A1 = a4[s + 16];
        float4 E0 = e4[s], E1 = e4[s + 16];

        float mk_raw = 0.f, p0 = 0.f, p1 = 0.f, p2 = 0.f;
        if (s == 0) {
            mk_raw = mask[gr];
            const float* pp = plab + gr * 3;
            p0 = pp[0]; p1 = pp[1]; p2 = pp[2];
        }

        float ssa = A0.x*A0.x + A0.y*A0.y + A0.z*A0.z + A0.w*A0.w
                  + A1.x*A1.x + A1.y*A1.y + A1.z*A1.z + A1.w*A1.w;
        float sse = E0.x*E0.x + E0.y*E0.y + E0.z*E0.z + E0.w*E0.w
                  + E1.x*E1.x + E1.y*E1.y + E1.z*E1.z + E1.w*E1.w;
        float dae = A0.x*E0.x + A0.y*E0.y + A0.z*E0.z + A0.w*E0.w
                  + A1.x*E1.x + A1.y*E1.y + A1.z*E1.z + A1.w*E1.w;

        ssa += __shfl_xor(ssa, 1); ssa += __shfl_xor(ssa, 2);
        ssa += __shfl_xor(ssa, 4); ssa += __shfl_xor(ssa, 8);
        sse += __shfl_xor(sse, 1); sse += __shfl_xor(sse, 2);
        sse += __shfl_xor(sse, 4); sse += __shfl_xor(sse, 8);
        dae += __shfl_xor(dae, 1); dae += __shfl_xor(dae, 2);
        dae += __shfl_xor(dae, 4); dae += __shfl_xor(dae, 8);

        const float inva = 1.0f / fmaxf(sqrtf(ssa), 1e-12f);
        const float inve = 1.0f / fmaxf(sqrtf(sse), 1e-12f);
        const float gs   = 2.0f * inva;     // fold 1/T + norm into A

        // pack this thread's two float4s (floats [4s,4s+4) and [64+4s,+4))
        unsigned pa0 = pk4(make_float4(gs*A0.x, gs*A0.y, gs*A0.z, gs*A0.w));
        unsigned pa1 = pk4(make_float4(gs*A1.x, gs*A1.y, gs*A1.z, gs*A1.w));

        // regroup: fragment u = floats [8u,8u+8)
        //   u<8:  pa0 of lanes 2u, 2u+1;   u>=8: pa1 of lanes 2u-16, 2u-15
        const int u = s;
        const int srcA = (gl & 48) + ((2 * u) & 15);
        unsigned q0A = __shfl(pa0, srcA), q0B = __shfl(pa0, srcA + 1);
        unsigned q1A = __shfl(pa1, srcA), q1B = __shfl(pa1, srcA + 1);
        unsigned lo = (u >= 8) ? q1A : q0A;
        unsigned hi = (u >= 8) ? q1B : q0B;
        unsigned long long frag =
            ((unsigned long long)hi << 32) | (unsigned long long)lo;

        if (valid) {
            afb[row * 16 + u] = frag;       // coalesced 8B/thread
            if (s == 0) {
                int lb = 0; float bst = p0;
                if (p1 > bst) { bst = p1; lb = 1; }   // first-max = argmax
                if (p2 > bst) { lb = 2; }
                rowmeta[row] = make_float4(2.0f * dae * inva * inve,
                                           mk_raw, (float)lb, 0.f);
            }
        }
    }
}

// ---- B: qt-in-LDS MFMA pass (R16 proven loop) ----
__global__ __launch_bounds__(512, 4) void pgc_mm(
    const unsigned long long* __restrict__ afb,
    const float4* __restrict__ rowmeta,
    const unsigned long long* __restrict__ qt,
    float* __restrict__ partial,
    int B)
{
    __shared__ unsigned long long qt_lds[6144];      // 49152 B
    __shared__ float s_red[8];

    const int tid = threadIdx.x;
    const int w   = tid >> 6;      // 0..7
    const int l   = tid & 63;
    const int lr  = l & 15;
    const int seg = l >> 4;
    const long rowbase = (long)blockIdx.x * 128 + w * 16;

    // ---- stage qt -> LDS: 6 glds/thread, fire-and-forget ----
    #pragma unroll
    for (int i = 0; i < 6; ++i) {
        glds16((const char*)qt + i * 8192 + w * 1024 + l * 16,
               (char*)qt_lds + i * 8192 + w * 1024);
    }

    // ---- tiny global reads: af fragments (32B) + own-row meta (16B) ----
    long grow = rowbase + lr;
    const bool valid = grow < (long)B;
    const long gr = valid ? grow : (long)B - 1;

    const unsigned long long* ap = afb + gr * 16 + seg * 4;
    long af[4];
    af[0] = (long)ap[0]; af[1] = (long)ap[1];
    af[2] = (long)ap[2]; af[3] = (long)ap[3];
    float4 meta = rowmeta[gr];
    const float def2 = meta.x;
    const float mk   = valid ? meta.y : 0.f;
    const int   lb   = (int)meta.z;

    __syncthreads();   // drains glds -> qt_lds ready

    // ---- 24-tile fp8 MFMA loop (R16 form) ----
    float S1[4] = {0.f, 0.f, 0.f, 0.f};
    f32x4 a23 = {0.f, 0.f, 0.f, 0.f};
    #pragma unroll
    for (int nt = 0; nt < 24; ++nt) {
        long b0 = (long)qt_lds[nt * 256 +       l];
        long b1 = (long)qt_lds[nt * 256 +  64 + l];
        long b2 = (long)qt_lds[nt * 256 + 128 + l];
        long b3 = (long)qt_lds[nt * 256 + 192 + l];
        f32x4 acc = {0.f, 0.f, 0.f, 0.f};
        acc = __builtin_amdgcn_mfma_f32_16x16x32_fp8_fp8(af[0], b0, acc, 0, 0, 0);
        acc = __builtin_amdgcn_mfma_f32_16x16x32_fp8_fp8(af[1], b1, acc, 0, 0, 0);
        acc = __builtin_amdgcn_mfma_f32_16x16x32_fp8_fp8(af[2], b2, acc, 0, 0, 0);
        acc = __builtin_amdgcn_mfma_f32_16x16x32_fp8_fp8(af[3], b3, acc, 0, 0, 0);
        if (nt < 23) {
            #pragma unroll
            for (int r = 0; r < 4; ++r)
                S1[r] += __expf(acc[r]);
        } else {
            a23 = acc;                 // lanes 7..9 hold class S2; lr<7 real
            if (lr < 7) {
                #pragma unroll
                for (int r = 0; r < 4; ++r)
                    S1[r] += __expf(acc[r]);
            }
        }
    }

    // ---- reduce S1 over the 16 column lanes ----
    #pragma unroll
    for (int r = 0; r < 4; ++r) {
        S1[r] += __shfl_xor(S1[r], 1);
        S1[r] += __shfl_xor(S1[r], 2);
        S1[r] += __shfl_xor(S1[r], 4);
        S1[r] += __shfl_xor(S1[r], 8);
    }

    // ---- epilogue: S2 via variable-lane shuffle from tile-23 acc ----
    float c = 0.f;
    #pragma unroll
    for (int r = 0; r < 4; ++r) {
        const int m   = seg * 4 + r;
        const int lbm = __shfl(lb, m);
        const float S2 = __shfl(a23[r], (l & 48) + 7 + lbm);
        const float d2 = __shfl(def2, m);
        const float mm = __shfl(mk, m);
        const float denom = __expf(d2) + S1[r];
        const float per = __logf(denom) - (S2 + d2) * INV126;
        if (lr == 0) c += mm * per;
    }
    c += __shfl_xor(c, 16);
    c += __shfl_xor(c, 32);
    if (l == 0) s_red[w] = c;
    __syncthreads();
    if (w == 0) {
        float v = (l < 8) ? s_red[l] : 0.f;
        v += __shfl_xor(v, 1); v += __shfl_xor(v, 2); v += __shfl_xor(v, 4);
        if (l == 0) partial[blockIdx.x] = v;
    }
}

// ---- finish: deterministic tree reduce ----
__global__ void pgc_finish(const float* __restrict__ partial,
                           float* __restrict__ out, int n, float invB)
{
    __shared__ float r[4];
    const int tid = threadIdx.x;
    float s = 0.f;
    for (int i = tid; i < n; i += 256) s += partial[i];
    s += __shfl_xor(s, 1);  s += __shfl_xor(s, 2);
    s += __shfl_xor(s, 4);  s += __shfl_xor(s, 8);
    s += __shfl_xor(s, 16); s += __shfl_xor(s, 32);
    if ((tid & 63) == 0) r[tid >> 6] = s;
    __syncthreads();
    if (tid == 0) out[0] = (r[0] + r[1] + r[2] + r[3]) * invB;
}

extern "C" void kernel_launch(void* const* d_in, const int* in_sizes, int n_in,
                              void* d_out, int out_size, void* d_ws, size_t ws_size,
                              hipStream_t stream)
{
    const float* act   = (const float*)d_in[0];
    const float* ema   = (const float*)d_in[1];
    const float* plab  = (const float*)d_in[2];
    const float* mask  = (const float*)d_in[3];
    const float* queue = (const float*)d_in[4];
    float* out = (float*)d_out;

    const int B = in_sizes[0] / D;
    const long Brnd = ((long)B + 255) & ~255L;

    // ws layout: qt 48KB | partial 16KB | rowmeta 16B*Brnd | afb 128B*Brnd
    unsigned long long* qt = (unsigned long long*)d_ws;
    float* partial = (float*)((char*)d_ws + QT_BYTES);
    float4* rowmeta = (float4*)((char*)d_ws + QT_BYTES + 16384);
    unsigned long long* afb =
        (unsigned long long*)((char*)d_ws + QT_BYTES + 16384 + Brnd * 16);

    pgc_prep<<<24, 256, 0, stream>>>(queue, qt);
    pgc_prep_qsum<<<3, 128, 0, stream>>>(queue, (unsigned char*)d_ws);

    const int gridA = (B + RPB - 1) / RPB;   // 1024
    pgc_rows<<<gridA, 256, 0, stream>>>(act, ema, plab, mask, afb, rowmeta, B);

    const int gridB = (B + 127) / 128;       // 1024
    pgc_mm<<<gridB, 512, 0, stream>>>(afb, rowmeta, qt, partial, B);

    pgc_finish<<<1, 256, 0, stream>>>(partial, out, gridB, 1.0f / (float)B);
}